// Round 3
// baseline (251.511 us; speedup 1.0000x reference)
//
#include <hip/hip_runtime.h>
#include <cstdint>
#include <cstddef>

#define N_TOK 32768
#define DIM   1024
#define NE    64
#define RPB   64          // rows per block = lanes per wave
#define KQ    256         // k range per quarter-wave
#define RSTR  36          // padded reduction stride (floats) to spread banks

typedef __attribute__((ext_vector_type(16))) float f16v;
typedef const __attribute__((address_space(4))) float*  cfp;   // constant AS -> s_load
typedef const __attribute__((address_space(4))) f16v*   cfp16;

__global__ __launch_bounds__(512, 4) void router_kernel(
    const float* __restrict__ x, const float* __restrict__ W,
    const float* __restrict__ bias, float* __restrict__ probs,
    float* __restrict__ idxo) {
  // epilogue-only LDS: k-reduction (padded) + cross-half merge
  __shared__ float  red[2][3][RPB][RSTR];   // 55.3 KB
  __shared__ float4 mg[2][RPB];             // 2 KB

  const int tid  = threadIdx.x;
  const int lane = tid & 63;
  const int w    = __builtin_amdgcn_readfirstlane(tid >> 6);  // 0..7
  const int eh   = w & 1;        // expert half: experts eh*32 .. eh*32+31
  const int kq   = w >> 1;       // k quarter:   k in [kq*256, kq*256+256)
  const int r0   = blockIdx.x * RPB;
  const int row  = r0 + lane;

  // ---- zero-fill this block's probs tile, fully coalesced (1024 float4) ----
  {
    float4* pt = (float4*)(probs + (size_t)r0 * NE);
    const float4 z = make_float4(0.f, 0.f, 0.f, 0.f);
    pt[tid]       = z;
    pt[tid + 512] = z;
  }

  // ---- main GEMM: lane = row; W streamed through SGPRs (s_load via AS4) ----
  float acc[32];
#pragma unroll
  for (int e = 0; e < 32; ++e) acc[e] = 0.0f;

  const float* xr = x + (size_t)row * DIM + kq * KQ;          // this lane's row slice
  cfp WC = (cfp)(uintptr_t)(W + (size_t)kq * KQ * NE + eh * 32);

  for (int k4 = 0; k4 < KQ / 4; ++k4) {
    const float4 xv = *(const float4*)(xr + k4 * 4);
#pragma unroll
    for (int j = 0; j < 4; ++j) {
      const int k = k4 * 4 + j;
      const f16v wa = *(cfp16)(WC + (size_t)k * NE);          // s_load_dwordx16
      const f16v wb = *(cfp16)(WC + (size_t)k * NE + 16);     // s_load_dwordx16
      const float xc = (j == 0) ? xv.x : (j == 1) ? xv.y : (j == 2) ? xv.z : xv.w;
#pragma unroll
      for (int e = 0; e < 16; ++e) acc[e]      = fmaf(wa[e], xc, acc[e]);
#pragma unroll
      for (int e = 0; e < 16; ++e) acc[16 + e] = fmaf(wb[e], xc, acc[16 + e]);
    }
  }

  // ---- k-reduction across the 4 quarter-waves (per expert half) ----
  __syncthreads();
  if (kq > 0) {
#pragma unroll
    for (int q = 0; q < 8; ++q)
      *(float4*)&red[eh][kq - 1][lane][q * 4] =
          make_float4(acc[q*4+0], acc[q*4+1], acc[q*4+2], acc[q*4+3]);
  }
  __syncthreads();

  if (kq == 0) {
#pragma unroll
    for (int t = 0; t < 3; ++t)
#pragma unroll
      for (int q = 0; q < 8; ++q) {
        float4 r = *(const float4*)&red[eh][t][lane][q * 4];
        acc[q*4+0] += r.x; acc[q*4+1] += r.y; acc[q*4+2] += r.z; acc[q*4+3] += r.w;
      }
    // bias (scalar loads), then top-2 of this 32-expert half (tie -> lower idx)
    cfp bC = (cfp)(uintptr_t)(bias + eh * 32);
#pragma unroll
    for (int e = 0; e < 32; ++e) acc[e] += bC[e];

    float v1, v2; int j1, j2;
    if (acc[1] > acc[0]) { v1 = acc[1]; j1 = 1; v2 = acc[0]; j2 = 0; }
    else                 { v1 = acc[0]; j1 = 0; v2 = acc[1]; j2 = 1; }
#pragma unroll
    for (int e = 2; e < 32; ++e) {
      if (acc[e] > v1)      { v2 = v1; j2 = j1; v1 = acc[e]; j1 = e; }
      else if (acc[e] > v2) { v2 = acc[e]; j2 = e; }
    }
    mg[eh][lane] = make_float4(v1, v2, (float)(eh * 32 + j1), (float)(eh * 32 + j2));
  }
  __syncthreads();

  // ---- merge halves, softmax, scatter (half-1 indices are larger: '>' keeps ties low) ----
  if (w == 0) {
    const float4 a = mg[0][lane], b2 = mg[1][lane];
    float V1 = a.x, V2 = a.y, J1 = a.z, J2 = a.w;
    if (b2.x > V1) {
      const bool s = (b2.y > V1);
      V2 = s ? b2.y : V1; J2 = s ? b2.w : J1;
      V1 = b2.x; J1 = b2.z;
    } else if (b2.x > V2) { V2 = b2.x; J2 = b2.z; }

    const float e2 = __expf(V2 - V1);
    const float p1 = 1.0f / (1.0f + e2);
    const float p2 = e2 * p1;

    float* pr = probs + (size_t)row * NE;
    pr[(int)J1] = p1;            // zero-fill completed + drained at earlier barriers
    pr[(int)J2] = p2;
    *(float2*)(idxo + (size_t)row * 2) = make_float2(J1, J2);
  }
}

extern "C" void kernel_launch(void* const* d_in, const int* in_sizes, int n_in,
                              void* d_out, int out_size, void* d_ws, size_t ws_size,
                              hipStream_t stream) {
  (void)in_sizes; (void)n_in; (void)out_size; (void)d_ws; (void)ws_size;
  const float* x = (const float*)d_in[0];
  const float* W = (const float*)d_in[1];
  const float* b = (const float*)d_in[2];
  float* out  = (float*)d_out;
  float* idxo = out + (size_t)N_TOK * NE;   // indices chunk follows probs chunk

  dim3 grid(N_TOK / RPB);   // 512 blocks -> 2 blocks/CU, 16 waves/CU
  dim3 block(512);
  hipLaunchKernelGGL(router_kernel, grid, block, 0, stream, x, W, b, out, idxo);
}